// Round 1
// baseline (9683.569 us; speedup 1.0000x reference)
//
#include <hip/hip_runtime.h>
#include <hip/hip_bf16.h>
#include <cstdint>

typedef __hip_bfloat16 bf16;

static constexpr int GD = 128;
static constexpr int GD3 = GD * GD * GD;  // 2,097,152

// ---------------- voxelize: scatter-add points into (4, z, y, x) f32 grid ----------------
__global__ void voxelize_kernel(const float4* __restrict__ pts, float* __restrict__ grid, int N) {
    int i = blockIdx.x * 256 + threadIdx.x;
    if (i >= N) return;
    float4 p = pts[i];
    if (p.x < -32.f || p.x > 32.f || p.y < -32.f || p.y > 32.f || p.z < -32.f || p.z > 32.f) return;
    int cx = min(max((int)floorf((p.x + 32.f) * 2.f), 0), 127);
    int cy = min(max((int)floorf((p.y + 32.f) * 2.f), 0), 127);
    int cz = min(max((int)floorf((p.z + 32.f) * 2.f), 0), 127);
    int idx = (cz * 128 + cy) * 128 + cx;
    atomicAdd(grid + idx,           p.x);
    atomicAdd(grid + GD3 + idx,     p.y);
    atomicAdd(grid + 2 * GD3 + idx, p.z);
    atomicAdd(grid + 3 * GD3 + idx, p.w);
}

__global__ void cvt_bf16_kernel(const float* __restrict__ in, bf16* __restrict__ out, int n) {
    int i = blockIdx.x * 256 + threadIdx.x;
    if (i < n) out[i] = __float2bfloat16(in[i]);
}

// ---------------- direct conv3d(k=3,p=1,stride S) + BN(eval) + ReLU ----------------
// thread: one output voxel v, 4 consecutive output channels co0..co0+3
// grid: (Co/4, Dout^3/256)  -- co fastest so L2 keeps the input tile hot across co-groups
template <int CI, int S>
__global__ __launch_bounds__(256) void conv_bn_relu(
    const bf16* __restrict__ in, const float* __restrict__ w,
    const float* __restrict__ gamma, const float* __restrict__ beta,
    bf16* __restrict__ out, int Din, int Dout) {
    int v = blockIdx.y * 256 + threadIdx.x;
    int co0 = blockIdx.x * 4;
    int x = v % Dout;
    int t = v / Dout;
    int y = t % Dout;
    int z = t / Dout;
    int Din2 = Din * Din;
    float acc0 = 0.f, acc1 = 0.f, acc2 = 0.f, acc3 = 0.f;
    constexpr int WCO = CI * 27;  // weight stride between output channels

#pragma unroll 1
    for (int ci = 0; ci < CI; ++ci) {
        const bf16* inc = in + (long long)ci * Din * Din2;
        const float* wp = w + ((long long)co0 * CI + ci) * 27;
#pragma unroll
        for (int dz = 0; dz < 3; ++dz) {
            int zi = z * S + dz - 1;
            if ((unsigned)zi >= (unsigned)Din) continue;
#pragma unroll
            for (int dy = 0; dy < 3; ++dy) {
                int yi = y * S + dy - 1;
                if ((unsigned)yi >= (unsigned)Din) continue;
                const bf16* row = inc + zi * Din2 + yi * Din;
                const float* wrow = wp + (dz * 3 + dy) * 3;
#pragma unroll
                for (int dx = 0; dx < 3; ++dx) {
                    int xi = x * S + dx - 1;
                    if ((unsigned)xi >= (unsigned)Din) continue;
                    float iv = __bfloat162float(row[xi]);
                    acc0 = fmaf(iv, wrow[dx],           acc0);
                    acc1 = fmaf(iv, wrow[dx + WCO],     acc1);
                    acc2 = fmaf(iv, wrow[dx + 2 * WCO], acc2);
                    acc3 = fmaf(iv, wrow[dx + 3 * WCO], acc3);
                }
            }
        }
    }
    const float inv = 1.0f / sqrtf(1.0f + 1e-5f);  // BN: running_var=1
    long long outN = (long long)Dout * Dout * Dout;
    float r0 = fmaxf(fmaf(acc0, gamma[co0 + 0] * inv, beta[co0 + 0]), 0.f);
    float r1 = fmaxf(fmaf(acc1, gamma[co0 + 1] * inv, beta[co0 + 1]), 0.f);
    float r2 = fmaxf(fmaf(acc2, gamma[co0 + 2] * inv, beta[co0 + 2]), 0.f);
    float r3 = fmaxf(fmaf(acc3, gamma[co0 + 3] * inv, beta[co0 + 3]), 0.f);
    out[(long long)(co0 + 0) * outN + v] = __float2bfloat16(r0);
    out[(long long)(co0 + 1) * outN + v] = __float2bfloat16(r1);
    out[(long long)(co0 + 2) * outN + v] = __float2bfloat16(r2);
    out[(long long)(co0 + 3) * outN + v] = __float2bfloat16(r3);
}

// ---------------- BEV: max over y (axis 2 of (C,z,y,x)) ----------------
__global__ void bev_max_kernel(const bf16* __restrict__ feat, float* __restrict__ bev) {
    int i = blockIdx.x * 256 + threadIdx.x;  // i = (c*32+z)*32 + x, 262144 total
    int x = i & 31;
    int zc = i >> 5;  // c*32+z
    const bf16* p = feat + (long long)zc * 1024 + x;
    float m = __bfloat162float(p[0]);
#pragma unroll
    for (int yy = 1; yy < 32; ++yy) m = fmaxf(m, __bfloat162float(p[yy * 32]));
    bev[i] = m;
}

// ---------------- bilinear resize 32x32 -> 200x200, half-pixel, edge clamp ----------------
__global__ void resize_kernel(const float* __restrict__ bev, float* __restrict__ out) {
    int i = blockIdx.x * 256 + threadIdx.x;
    if (i >= 256 * 200 * 200) return;
    int ox = i % 200;
    int t = i / 200;
    int oy = t % 200;
    int c = t / 200;
    float fy = (oy + 0.5f) / 6.25f - 0.5f;   // scale = 200/32 = 6.25 exact
    float fx = (ox + 0.5f) / 6.25f - 0.5f;
    float fy0 = floorf(fy), fx0 = floorf(fx);
    float ty = fy - fy0, tx = fx - fx0;
    int y0 = min(max((int)fy0, 0), 31), y1 = min(max((int)fy0 + 1, 0), 31);
    int x0 = min(max((int)fx0, 0), 31), x1 = min(max((int)fx0 + 1, 0), 31);
    const float* bc = bev + c * 1024;
    float v00 = bc[y0 * 32 + x0], v01 = bc[y0 * 32 + x1];
    float v10 = bc[y1 * 32 + x0], v11 = bc[y1 * 32 + x1];
    float top = v00 + tx * (v01 - v00);
    float bot = v10 + tx * (v11 - v10);
    out[i] = top + ty * (bot - top);
}

extern "C" void kernel_launch(void* const* d_in, const int* in_sizes, int n_in,
                              void* d_out, int out_size, void* d_ws, size_t ws_size,
                              hipStream_t stream) {
    const float* points = (const float*)d_in[0];
    int N = in_sizes[0] / 4;
    const float *W[6], *Gm[6], *Bt[6];
    for (int i = 0; i < 6; ++i) {
        W[i]  = (const float*)d_in[1 + 3 * i];
        Gm[i] = (const float*)d_in[2 + 3 * i];
        Bt[i] = (const float*)d_in[3 + 3 * i];
    }

    // Workspace layout (ping-pong, 161 MB total):
    //   B (bf16, 128 MB) @ 0        -- also overlaps the f32 grid (32 MB) which dies after cvt
    //   A (bf16,  32 MB) @ 128 MB
    //   bev (f32,  1 MB) @ 160 MB
    char* ws = (char*)d_ws;
    float* gridF = (float*)ws;
    bf16* B = (bf16*)ws;
    bf16* A = (bf16*)(ws + (128ll << 20));
    float* bev = (float*)(ws + (160ll << 20));
    float* outp = (float*)d_out;

    hipMemsetAsync(gridF, 0, (size_t)4 * GD3 * sizeof(float), stream);
    voxelize_kernel<<<(N + 255) / 256, 256, 0, stream>>>((const float4*)points, gridF, N);
    cvt_bf16_kernel<<<(4 * GD3) / 256, 256, 0, stream>>>(gridF, A, 4 * GD3);

    // conv1: 4 -> 32, s1, 128^3 -> 128^3    A -> B
    conv_bn_relu<4, 1><<<dim3(8, 8192), 256, 0, stream>>>(A, W[0], Gm[0], Bt[0], B, 128, 128);
    // conv2: 32 -> 64, s2, 128^3 -> 64^3    B -> A
    conv_bn_relu<32, 2><<<dim3(16, 1024), 256, 0, stream>>>(B, W[1], Gm[1], Bt[1], A, 128, 64);
    // conv3: 64 -> 64, s1, 64^3             A -> B
    conv_bn_relu<64, 1><<<dim3(16, 1024), 256, 0, stream>>>(A, W[2], Gm[2], Bt[2], B, 64, 64);
    // conv4: 64 -> 128, s2, 64^3 -> 32^3    B -> A
    conv_bn_relu<64, 2><<<dim3(32, 128), 256, 0, stream>>>(B, W[3], Gm[3], Bt[3], A, 64, 32);
    // conv5: 128 -> 128, s1, 32^3           A -> B
    conv_bn_relu<128, 1><<<dim3(32, 128), 256, 0, stream>>>(A, W[4], Gm[4], Bt[4], B, 32, 32);
    // conv6: 128 -> 256, s1, 32^3           B -> A
    conv_bn_relu<128, 1><<<dim3(64, 128), 256, 0, stream>>>(B, W[5], Gm[5], Bt[5], A, 32, 32);

    bev_max_kernel<<<1024, 256, 0, stream>>>(A, bev);
    resize_kernel<<<40000, 256, 0, stream>>>(bev, outp);
}

// Round 2
// 1127.468 us; speedup vs baseline: 8.5888x; 8.5888x over previous
//
#include <hip/hip_runtime.h>
#include <cstdint>
#include <cstddef>

typedef __attribute__((ext_vector_type(8))) short short8;
typedef __attribute__((ext_vector_type(4))) float f32x4;

__device__ __forceinline__ float bf2f(unsigned short u) { return __uint_as_float(((unsigned)u) << 16); }
__device__ __forceinline__ unsigned short f2bf(float f) {
    unsigned u = __float_as_uint(f);
    return (unsigned short)((u + 0x7fffu + ((u >> 16) & 1u)) >> 16);
}

static constexpr float BN_INV = 0.9999950000374997f;  // 1/sqrt(1+1e-5)

// ---------------- voxelize: scatter-add into padded channels-last f32 grid (130,130,130,4) ----------
__global__ __launch_bounds__(256) void voxelize_kernel(const float4* __restrict__ pts,
                                                       float* __restrict__ grid, int N) {
    int i = blockIdx.x * 256 + threadIdx.x;
    if (i >= N) return;
    float4 p = pts[i];
    if (p.x < -32.f || p.x > 32.f || p.y < -32.f || p.y > 32.f || p.z < -32.f || p.z > 32.f) return;
    int cx = min(max((int)floorf((p.x + 32.f) * 2.f), 0), 127);
    int cy = min(max((int)floorf((p.y + 32.f) * 2.f), 0), 127);
    int cz = min(max((int)floorf((p.z + 32.f) * 2.f), 0), 127);
    int idx = ((((cz + 1) * 130) + (cy + 1)) * 130 + (cx + 1)) * 4;
    atomicAdd(grid + idx + 0, p.x);
    atomicAdd(grid + idx + 1, p.y);
    atomicAdd(grid + idx + 2, p.z);
    atomicAdd(grid + idx + 3, p.w);
}

__global__ __launch_bounds__(256) void cvt_kernel(const float* __restrict__ g,
                                                  unsigned short* __restrict__ o, int n) {
    int i = blockIdx.x * 256 + threadIdx.x;
    if (i < n) o[i] = f2bf(g[i]);
}

// ---------------- weight repacks (fold BN gamma scale) ----------------
// MFMA layers: out[k][co][ci] bf16
__global__ __launch_bounds__(256) void repack_w(const float* __restrict__ w, const float* __restrict__ g,
                                                unsigned short* __restrict__ o, int Co, int CI) {
    int i = blockIdx.x * 256 + threadIdx.x;
    int total = 27 * Co * CI;
    if (i >= total) return;
    int ci = i % CI;
    int t = i / CI;
    int co = t % Co;
    int k = t / Co;
    float v = w[((size_t)(co * CI + ci)) * 27 + k] * g[co] * BN_INV;
    o[i] = f2bf(v);
}
// conv1: out[k][ci][co] f32
__global__ __launch_bounds__(256) void repack_w1(const float* __restrict__ w, const float* __restrict__ g,
                                                 float* __restrict__ o) {
    int i = blockIdx.x * 256 + threadIdx.x;
    if (i >= 3456) return;
    int co = i % 32;
    int t = i / 32;
    int ci = t % 4;
    int k = t / 4;
    o[i] = w[(co * 4 + ci) * 27 + k] * g[co] * BN_INV;
}

// ---------------- conv1 direct: 4 -> 32 ch, stride 1, padded in (130^3,4), slab out ----------------
// thread: 2 consecutive x voxels, all 32 co. Weights wave-uniform -> SGPR.
__global__ __launch_bounds__(256) void conv1_direct(
    const unsigned short* __restrict__ in, const float* __restrict__ wc,
    const float* __restrict__ beta, unsigned short* __restrict__ out,
    int zstart, int r0) {
    int p = blockIdx.x * 256 + threadIdx.x;
    int x0 = (p & 63) * 2;
    int ry = p >> 6;
    int y = ry & 127;
    int z = zstart + (ry >> 7);
    float acc0[32], acc1[32];
#pragma unroll
    for (int c = 0; c < 32; ++c) { acc0[c] = 0.f; acc1[c] = 0.f; }
#pragma unroll 1
    for (int dz = 0; dz < 3; ++dz) {
#pragma unroll 1
        for (int dy = 0; dy < 3; ++dy) {
            const unsigned short* rp = in + ((((z + dz) * 130) + (y + dy)) * 130 + x0) * 4;
            float f[16];
#pragma unroll
            for (int j = 0; j < 4; ++j) {
                uint2 d = *(const uint2*)(rp + j * 4);
                f[j * 4 + 0] = __uint_as_float(d.x << 16);
                f[j * 4 + 1] = __uint_as_float(d.x & 0xffff0000u);
                f[j * 4 + 2] = __uint_as_float(d.y << 16);
                f[j * 4 + 3] = __uint_as_float(d.y & 0xffff0000u);
            }
            const float* wb9 = wc + (dz * 3 + dy) * 3 * 4 * 32;
#pragma unroll
            for (int dx = 0; dx < 3; ++dx)
#pragma unroll
                for (int ci = 0; ci < 4; ++ci) {
                    const float* wrow = wb9 + (dx * 4 + ci) * 32;
                    float a0 = f[dx * 4 + ci];
                    float a1 = f[dx * 4 + ci + 4];
#pragma unroll
                    for (int co = 0; co < 32; ++co) {
                        acc0[co] = fmaf(a0, wrow[co], acc0[co]);
                        acc1[co] = fmaf(a1, wrow[co], acc1[co]);
                    }
                }
        }
    }
    int r = z - zstart + r0;
    unsigned short* op = out + (((r * 130) + (y + 1)) * 130 + (x0 + 1)) * 32;
#pragma unroll
    for (int j = 0; j < 8; ++j) {
        ushort4 u;
        u.x = f2bf(fmaxf(acc0[j * 4 + 0] + beta[j * 4 + 0], 0.f));
        u.y = f2bf(fmaxf(acc0[j * 4 + 1] + beta[j * 4 + 1], 0.f));
        u.z = f2bf(fmaxf(acc0[j * 4 + 2] + beta[j * 4 + 2], 0.f));
        u.w = f2bf(fmaxf(acc0[j * 4 + 3] + beta[j * 4 + 3], 0.f));
        *(ushort4*)(op + j * 4) = u;
    }
#pragma unroll
    for (int j = 0; j < 8; ++j) {
        ushort4 u;
        u.x = f2bf(fmaxf(acc1[j * 4 + 0] + beta[j * 4 + 0], 0.f));
        u.y = f2bf(fmaxf(acc1[j * 4 + 1] + beta[j * 4 + 1], 0.f));
        u.z = f2bf(fmaxf(acc1[j * 4 + 2] + beta[j * 4 + 2], 0.f));
        u.w = f2bf(fmaxf(acc1[j * 4 + 3] + beta[j * 4 + 3], 0.f));
        *(ushort4*)(op + 32 + j * 4) = u;
    }
}

// ---------------- MFMA implicit-GEMM conv: per offset k, C[co,vox] += Wk[co,ci] * X[ci,vox] ----------
// Block: 256 thr = 4 waves, tile 64 co x 128 vox. Channels-last padded input, no bounds checks.
template <int CI, int S, int KC, int CIp, int KCp>
__global__ __launch_bounds__(256) void conv_mfma(
    const unsigned short* __restrict__ in, const unsigned short* __restrict__ wb,
    const float* __restrict__ beta, unsigned short* __restrict__ out,
    int D, int lgD, int Xp, int Xpo, int Co, int zin_base, int v_off) {

    constexpr int OPB = KC / 8;   // 16B octets per vox per B-chunk
    constexpr int NS = KC / 16;   // B staging slots per thread
    constexpr int NA = CI / 32;   // A staging slots per thread
    __shared__ unsigned short sA[64 * CIp];
    __shared__ unsigned short sB[128 * KCp];

    const int tid = threadIdx.x;
    const int lane = tid & 63;
    const int wv = tid >> 6;
    const int m = lane & 15;
    const int q = lane >> 4;
    const int co0 = blockIdx.x * 64;
    const int v0 = v_off + blockIdx.y * 128;

    int bg[NS], bl[NS];
#pragma unroll
    for (int s = 0; s < NS; ++s) {
        int idx = tid + s * 256;
        int voxL = idx / OPB;
        int oct = idx % OPB;
        int vg = v0 + voxL;
        int x = vg & (D - 1);
        int ryv = vg >> lgD;
        int y = ryv & (D - 1);
        int z = ryv >> lgD;
        bg[s] = ((z * S * Xp + y * S) * Xp + x * S) * CI + oct * 8;
        bl[s] = voxL * KCp + oct * 8;
    }
    int ag[NA], al[NA];
#pragma unroll
    for (int j = 0; j < NA; ++j) {
        int idx = tid + j * 256;
        int coA = idx / (CI / 8);
        int octA = idx % (CI / 8);
        ag[j] = coA * CI + octA * 8;
        al[j] = coA * CIp + octA * 8;
    }
    int aoff[4], boff[2];
#pragma unroll
    for (int cot = 0; cot < 4; ++cot) aoff[cot] = (cot * 16 + m) * CIp + q * 8;
#pragma unroll
    for (int vt = 0; vt < 2; ++vt) boff[vt] = (wv * 32 + vt * 16 + m) * KCp + q * 8;

    f32x4 acc[4][2];
#pragma unroll
    for (int cot = 0; cot < 4; ++cot)
#pragma unroll
        for (int vt = 0; vt < 2; ++vt) acc[cot][vt] = (f32x4){0.f, 0.f, 0.f, 0.f};

#pragma unroll 1
    for (int k = 0; k < 27; ++k) {
        int dz = k / 9;
        int rr = k - dz * 9;
        int dy = rr / 3;
        int dx = rr - dy * 3;
        int koff = (((dz - zin_base) * Xp + dy) * Xp + dx) * CI;
        const unsigned short* wk = wb + ((size_t)(k * Co + co0)) * CI;
#pragma unroll
        for (int j = 0; j < NA; ++j)
            *(short8*)(sA + al[j]) = *(const short8*)(wk + ag[j]);
#pragma unroll 1
        for (int c0 = 0; c0 < CI; c0 += KC) {
#pragma unroll
            for (int s = 0; s < NS; ++s)
                *(short8*)(sB + bl[s]) = *(const short8*)(in + bg[s] + koff + c0);
            __syncthreads();
#pragma unroll
            for (int kc = 0; kc < KC; kc += 32) {
                short8 bv[2];
#pragma unroll
                for (int vt = 0; vt < 2; ++vt) bv[vt] = *(const short8*)(sB + boff[vt] + kc);
#pragma unroll
                for (int cot = 0; cot < 4; ++cot) {
                    short8 av = *(const short8*)(sA + aoff[cot] + c0 + kc);
#pragma unroll
                    for (int vt = 0; vt < 2; ++vt)
                        acc[cot][vt] = __builtin_amdgcn_mfma_f32_16x16x32_bf16(av, bv[vt], acc[cot][vt], 0, 0, 0);
                }
            }
            __syncthreads();
        }
    }
    // epilogue: relu(acc + beta) -> bf16, channels-last padded store
    float4 bt[4];
#pragma unroll
    for (int cot = 0; cot < 4; ++cot) bt[cot] = *(const float4*)(beta + co0 + cot * 16 + q * 4);
#pragma unroll
    for (int vt = 0; vt < 2; ++vt) {
        int vg = v0 + wv * 32 + vt * 16 + m;
        int x = vg & (D - 1);
        int ryv = vg >> lgD;
        int y = ryv & (D - 1);
        int z = ryv >> lgD;
        size_t ob = (((size_t)(z + 1) * Xpo + (y + 1)) * Xpo + (x + 1)) * Co + co0;
#pragma unroll
        for (int cot = 0; cot < 4; ++cot) {
            f32x4 v = acc[cot][vt];
            ushort4 u;
            u.x = f2bf(fmaxf(v.x + bt[cot].x, 0.f));
            u.y = f2bf(fmaxf(v.y + bt[cot].y, 0.f));
            u.z = f2bf(fmaxf(v.z + bt[cot].z, 0.f));
            u.w = f2bf(fmaxf(v.w + bt[cot].w, 0.f));
            *(ushort4*)(out + ob + cot * 16 + q * 4) = u;
        }
    }
}

// ---------------- BEV max over y: O6p (34,34,34,256) -> bev[(z*32+x)*256+c] f32 ----------------
__global__ __launch_bounds__(256) void bev_max_kernel(const unsigned short* __restrict__ feat,
                                                      float* __restrict__ bev) {
    int z = blockIdx.x >> 5;
    int x = blockIdx.x & 31;
    int c = threadIdx.x;
    const unsigned short* p = feat + ((((z + 1) * 34) + 1) * 34 + (x + 1)) * 256 + c;
    float mx = 0.f;  // post-ReLU values are >= 0
#pragma unroll
    for (int y = 0; y < 32; ++y) mx = fmaxf(mx, bf2f(p[y * 34 * 256]));
    bev[(z * 32 + x) * 256 + c] = mx;
}

// ---------------- bilinear resize 32x32 -> 200x200, half-pixel, edge clamp ----------------
__global__ __launch_bounds__(256) void resize_kernel(const float* __restrict__ bev,
                                                     float* __restrict__ out) {
    int i = blockIdx.x * 256 + threadIdx.x;
    if (i >= 256 * 200 * 200) return;
    int ox = i % 200;
    int t = i / 200;
    int oy = t % 200;
    int c = t / 200;
    const float sc = 32.0f / 200.0f;
    float fy = (oy + 0.5f) * sc - 0.5f;
    float fx = (ox + 0.5f) * sc - 0.5f;
    float fy0 = floorf(fy), fx0 = floorf(fx);
    float ty = fy - fy0, tx = fx - fx0;
    int y0 = min(max((int)fy0, 0), 31), y1 = min(max((int)fy0 + 1, 0), 31);
    int x0 = min(max((int)fx0, 0), 31), x1 = min(max((int)fx0 + 1, 0), 31);
    float v00 = bev[(y0 * 32 + x0) * 256 + c], v01 = bev[(y0 * 32 + x1) * 256 + c];
    float v10 = bev[(y1 * 32 + x0) * 256 + c], v11 = bev[(y1 * 32 + x1) * 256 + c];
    float top = v00 + tx * (v01 - v00);
    float bot = v10 + tx * (v11 - v10);
    out[i] = top + ty * (bot - top);
}

extern "C" void kernel_launch(void* const* d_in, const int* in_sizes, int n_in,
                              void* d_out, int out_size, void* d_ws, size_t ws_size,
                              hipStream_t stream) {
    const float* points = (const float*)d_in[0];
    int N = in_sizes[0] / 4;
    const float *W[6], *G[6], *B[6];
    for (int i = 0; i < 6; ++i) {
        W[i] = (const float*)d_in[1 + 3 * i];
        G[i] = (const float*)d_in[2 + 3 * i];
        B[i] = (const float*)d_in[3 + 3 * i];
    }

    // ---- workspace layout (bytes), peak ~134 MiB < 161 MiB proven ----
    char* ws = (char*)d_ws;
    const size_t MiB = 1ull << 20;
    unsigned short* X0p = (unsigned short*)(ws);                 // 130^3*4*2   = 17,576,000
    float* gridF = (float*)(ws + 18 * MiB);                      // 130^3*4*4   = 35,152,000
    unsigned short* O1s = (unsigned short*)(ws + 18 * MiB);      // 65*130*130*32*2 = 70,304,000 (over dead gridF)
    unsigned short* O2p = (unsigned short*)(ws + 86 * MiB);      // 66^3*64*2   = 36,799,488
    unsigned short* O3p = (unsigned short*)(ws);                 // 36,799,488 (over dead X0p/O1s-head)
    unsigned short* O4p = (unsigned short*)(ws + 37 * MiB);      // 34^3*128*2  = 10,061,824
    unsigned short* O5p = (unsigned short*)(ws + 48 * MiB);      // 10,061,824
    unsigned short* O6p = (unsigned short*)(ws + 59 * MiB);      // 34^3*256*2  = 20,123,648
    float* bev = (float*)(ws + 80 * MiB);                        // 262144*4 = 1,048,576
    float* wc1 = (float*)(ws + 130 * MiB);                       // 13,824
    unsigned short* wb2 = (unsigned short*)(ws + 130 * MiB + 16384);
    unsigned short* wb3 = wb2 + 27 * 64 * 32;
    unsigned short* wb4 = wb3 + 27 * 64 * 64;
    unsigned short* wb5 = wb4 + 27 * 128 * 64;
    unsigned short* wb6 = wb5 + 27 * 128 * 128;

    // weight repacks (independent of activations)
    repack_w1<<<14, 256, 0, stream>>>(W[0], G[0], wc1);
    repack_w<<<216, 256, 0, stream>>>(W[1], G[1], wb2, 64, 32);
    repack_w<<<432, 256, 0, stream>>>(W[2], G[2], wb3, 64, 64);
    repack_w<<<864, 256, 0, stream>>>(W[3], G[3], wb4, 128, 64);
    repack_w<<<1728, 256, 0, stream>>>(W[4], G[4], wb5, 128, 128);
    repack_w<<<3456, 256, 0, stream>>>(W[5], G[5], wb6, 256, 128);

    // voxelize -> padded f32 grid -> bf16 padded channels-last
    hipMemsetAsync(gridF, 0, 35152000, stream);
    hipMemsetAsync(O2p, 0, 36799488, stream);
    voxelize_kernel<<<(N + 255) / 256, 256, 0, stream>>>((const float4*)points, gridF, N);
    cvt_kernel<<<34329, 256, 0, stream>>>(gridF, X0p, 8788000);

    // conv1/conv2 in two z-slabs (O1s holds 65 padded-z rows)
    hipMemsetAsync(O1s, 0, 70304000, stream);  // after cvt (kills gridF region)
    conv1_direct<<<2048, 256, 0, stream>>>(X0p, wc1, B[0], O1s, 0, 1);
    conv_mfma<32, 2, 32, 48, 48><<<dim3(1, 1024), 256, 0, stream>>>(O1s, wb2, B[1], O2p, 64, 6, 130, 66, 64, 0, 0);
    conv1_direct<<<2080, 256, 0, stream>>>(X0p, wc1, B[0], O1s, 63, 0);
    conv_mfma<32, 2, 32, 48, 48><<<dim3(1, 1024), 256, 0, stream>>>(O1s, wb2, B[1], O2p, 64, 6, 130, 66, 64, 64, 131072);

    // remaining buffers become free only after conv2-h2
    hipMemsetAsync(O3p, 0, 36799488, stream);
    hipMemsetAsync(O4p, 0, 10061824, stream);
    hipMemsetAsync(O5p, 0, 10061824, stream);
    hipMemsetAsync(O6p, 0, 20123648, stream);

    // conv3: 64->64, s1, 64^3
    conv_mfma<64, 1, 64, 72, 72><<<dim3(1, 2048), 256, 0, stream>>>(O2p, wb3, B[2], O3p, 64, 6, 66, 66, 64, 0, 0);
    // conv4: 64->128, s2, 64^3 -> 32^3
    conv_mfma<64, 2, 64, 72, 72><<<dim3(2, 256), 256, 0, stream>>>(O3p, wb4, B[3], O4p, 32, 5, 66, 34, 128, 0, 0);
    // conv5: 128->128, s1, 32^3
    conv_mfma<128, 1, 64, 136, 72><<<dim3(2, 256), 256, 0, stream>>>(O4p, wb5, B[4], O5p, 32, 5, 34, 34, 128, 0, 0);
    // conv6: 128->256, s1, 32^3
    conv_mfma<128, 1, 64, 136, 72><<<dim3(4, 256), 256, 0, stream>>>(O5p, wb6, B[5], O6p, 32, 5, 34, 34, 256, 0, 0);

    bev_max_kernel<<<1024, 256, 0, stream>>>(O6p, bev);
    resize_kernel<<<40000, 256, 0, stream>>>(bev, (float*)d_out);
}